// Round 2
// baseline (2378.100 us; speedup 1.0000x reference)
//
#include <hip/hip_runtime.h>
#include <hip/hip_bf16.h>

#define D_ 2048
#define H_ 16
#define KVH_ 4
#define HD_ 128
#define E_ 32
#define TOPK_ 8
#define F_ 768
#define NB_ 2
#define SS_ 1024
#define NT_ 2048        // NB_*SS_ tokens
#define NPAIR_ 16384    // NT_*TOPK_

typedef __attribute__((ext_vector_type(8))) short short8;
typedef __attribute__((ext_vector_type(4))) float floatx4;
typedef __attribute__((ext_vector_type(4))) unsigned short ushortx4;

__device__ __forceinline__ unsigned short f2bf(float f) {
  union { float f; unsigned u; } v; v.f = f;
  unsigned r = v.u + 0x7FFFu + ((v.u >> 16) & 1u);
  return (unsigned short)(r >> 16);
}
__device__ __forceinline__ float bf2f(unsigned short h) {
  union { unsigned u; float f; } v; v.u = ((unsigned)h) << 16;
  return v.f;
}
// split fp32 into hi+lo bf16 (v - hi is exact in fp32)
__device__ __forceinline__ void split2(float v, unsigned short& hi, unsigned short& lo) {
  unsigned short h = f2bf(v);
  hi = h;
  lo = f2bf(v - bf2f(h));
}

// ---------------- RMSNorm: fp32 in -> fp32 out ----------------
__global__ __launch_bounds__(256) void rms_kernel(const float* __restrict__ in,
                                                  const float* __restrict__ sc,
                                                  float* __restrict__ out) {
  __shared__ float red[4];
  int row = blockIdx.x, tid = threadIdx.x;
  const float4* x4 = (const float4*)(in + (size_t)row * D_);
  float4 a = x4[tid], b = x4[tid + 256];
  float ss = a.x*a.x + a.y*a.y + a.z*a.z + a.w*a.w
           + b.x*b.x + b.y*b.y + b.z*b.z + b.w*b.w;
  #pragma unroll
  for (int off = 1; off < 64; off <<= 1) ss += __shfl_xor(ss, off);
  if ((tid & 63) == 0) red[tid >> 6] = ss;
  __syncthreads();
  float r = rsqrtf((red[0] + red[1] + red[2] + red[3]) * (1.0f / D_) + 1e-6f);
  const float4* s4 = (const float4*)sc;
  float4 sa = s4[tid], sb = s4[tid + 256];
  float4 o1 = make_float4(a.x*r*sa.x, a.y*r*sa.y, a.z*r*sa.z, a.w*r*sa.w);
  float4 o2 = make_float4(b.x*r*sb.x, b.y*r*sb.y, b.z*r*sb.z, b.w*r*sb.w);
  *(float4*)(out + (size_t)row * D_ + tid * 4) = o1;
  *(float4*)(out + (size_t)row * D_ + 1024 + tid * 4) = o2;
}

// ---------------- GEMM: fp32 A [M][K] x fp32 B [K][N] -> fp32, split-bf16 MFMA ----------------
// EPI 0: out = acc ; EPI 1: out = res + acc
#define LDA_ 48
template<int EPI>
__global__ __launch_bounds__(256) void gemm_kernel(const float* __restrict__ A,
                                                   const float* __restrict__ B,
                                                   const float* __restrict__ res,
                                                   float* __restrict__ out,
                                                   int M, int Nn, int K) {
  __shared__ unsigned short Ah[64 * LDA_], Al[64 * LDA_];
  __shared__ unsigned short Bh[64 * LDA_], Bl[64 * LDA_];
  int tid = threadIdx.x;
  int l = tid & 63, wid = tid >> 6;
  int lr = l & 15, lk = (l >> 4) * 8;
  int m0 = blockIdx.y * 64, n0 = blockIdx.x * 64;
  int wr = (wid >> 1) * 32, wc = (wid & 1) * 32;
  int ar = tid >> 2, akq = (tid & 3) * 8;
  int bkr = tid >> 3, bnq = (tid & 7) * 8;
  floatx4 acc[2][2];
  #pragma unroll
  for (int i = 0; i < 2; ++i)
    #pragma unroll
    for (int j = 0; j < 2; ++j) acc[i][j] = (floatx4){0.f, 0.f, 0.f, 0.f};
  const float* Arow = A + (size_t)(m0 + ar) * K + akq;
  for (int k0 = 0; k0 < K; k0 += 32) {
    float4 a0 = *(const float4*)(Arow + k0);
    float4 a1 = *(const float4*)(Arow + k0 + 4);
    const float* bp = B + (size_t)(k0 + bkr) * Nn + n0 + bnq;
    float4 b0 = *(const float4*)bp;
    float4 b1 = *(const float4*)(bp + 4);
    __syncthreads();
    float av[8] = {a0.x,a0.y,a0.z,a0.w,a1.x,a1.y,a1.z,a1.w};
    float bv[8] = {b0.x,b0.y,b0.z,b0.w,b1.x,b1.y,b1.z,b1.w};
    #pragma unroll
    for (int e = 0; e < 8; ++e) {
      split2(av[e], Ah[ar * LDA_ + akq + e], Al[ar * LDA_ + akq + e]);
      split2(bv[e], Bh[(bnq + e) * LDA_ + bkr], Bl[(bnq + e) * LDA_ + bkr]);
    }
    __syncthreads();
    short8 af0h = *(const short8*)&Ah[(wr + lr) * LDA_ + lk];
    short8 af0l = *(const short8*)&Al[(wr + lr) * LDA_ + lk];
    short8 af1h = *(const short8*)&Ah[(wr + 16 + lr) * LDA_ + lk];
    short8 af1l = *(const short8*)&Al[(wr + 16 + lr) * LDA_ + lk];
    short8 bf0h = *(const short8*)&Bh[(wc + lr) * LDA_ + lk];
    short8 bf0l = *(const short8*)&Bl[(wc + lr) * LDA_ + lk];
    short8 bf1h = *(const short8*)&Bh[(wc + 16 + lr) * LDA_ + lk];
    short8 bf1l = *(const short8*)&Bl[(wc + 16 + lr) * LDA_ + lk];
    acc[0][0] = __builtin_amdgcn_mfma_f32_16x16x32_bf16(af0h, bf0h, acc[0][0], 0, 0, 0);
    acc[0][0] = __builtin_amdgcn_mfma_f32_16x16x32_bf16(af0h, bf0l, acc[0][0], 0, 0, 0);
    acc[0][0] = __builtin_amdgcn_mfma_f32_16x16x32_bf16(af0l, bf0h, acc[0][0], 0, 0, 0);
    acc[0][1] = __builtin_amdgcn_mfma_f32_16x16x32_bf16(af0h, bf1h, acc[0][1], 0, 0, 0);
    acc[0][1] = __builtin_amdgcn_mfma_f32_16x16x32_bf16(af0h, bf1l, acc[0][1], 0, 0, 0);
    acc[0][1] = __builtin_amdgcn_mfma_f32_16x16x32_bf16(af0l, bf1h, acc[0][1], 0, 0, 0);
    acc[1][0] = __builtin_amdgcn_mfma_f32_16x16x32_bf16(af1h, bf0h, acc[1][0], 0, 0, 0);
    acc[1][0] = __builtin_amdgcn_mfma_f32_16x16x32_bf16(af1h, bf0l, acc[1][0], 0, 0, 0);
    acc[1][0] = __builtin_amdgcn_mfma_f32_16x16x32_bf16(af1l, bf0h, acc[1][0], 0, 0, 0);
    acc[1][1] = __builtin_amdgcn_mfma_f32_16x16x32_bf16(af1h, bf1h, acc[1][1], 0, 0, 0);
    acc[1][1] = __builtin_amdgcn_mfma_f32_16x16x32_bf16(af1h, bf1l, acc[1][1], 0, 0, 0);
    acc[1][1] = __builtin_amdgcn_mfma_f32_16x16x32_bf16(af1l, bf1h, acc[1][1], 0, 0, 0);
  }
  int rq = (l >> 4) * 4;
  #pragma unroll
  for (int i = 0; i < 2; ++i)
    #pragma unroll
    for (int j = 0; j < 2; ++j)
      #pragma unroll
      for (int r = 0; r < 4; ++r) {
        size_t idx = (size_t)(m0 + wr + i * 16 + rq + r) * Nn + (n0 + wc + j * 16 + lr);
        float v = acc[i][j][r];
        if (EPI == 1) v += res[idx];
        out[idx] = v;
      }
}

// ---------------- per-head RMSNorm + RoPE (in-place, fp32) ----------------
__global__ __launch_bounds__(256) void qknorm_rope_kernel(float* __restrict__ qb,
                                                          float* __restrict__ kb,
                                                          const float* __restrict__ qs,
                                                          const float* __restrict__ ks) {
  int gw = blockIdx.x * 4 + (threadIdx.x >> 6);
  int l = threadIdx.x & 63;
  float* ptr; const float* sc; int t;
  if (gw < NT_ * H_) { ptr = qb + (size_t)gw * HD_; sc = qs; t = gw >> 4; }
  else { int r = gw - NT_ * H_; ptr = kb + (size_t)r * HD_; sc = ks; t = r >> 2; }
  int pos = t & (SS_ - 1);
  float2 x = *(float2*)(ptr + 2 * l);
  float p2 = x.x * x.x + x.y * x.y;
  #pragma unroll
  for (int off = 1; off < 64; off <<= 1) p2 += __shfl_xor(p2, off);
  float rms = rsqrtf(p2 * (1.0f / HD_) + 1e-6f);
  float nx = x.x * rms * sc[2 * l];
  float ny = x.y * rms * sc[2 * l + 1];
  int j0 = (2 * l) & 63;
  float ang0 = pos * __expf(-(float)j0 * (13.815510557964274f / 64.0f));
  float ang1 = pos * __expf(-(float)(j0 + 1) * (13.815510557964274f / 64.0f));
  float s0, c0, s1, c1;
  sincosf(ang0, &s0, &c0);
  sincosf(ang1, &s1, &c1);
  float ox = __shfl_xor(nx, 32);
  float oy = __shfl_xor(ny, 32);
  float r0, r1;
  if (l < 32) { r0 = nx * c0 - ox * s0; r1 = ny * c1 - oy * s1; }
  else        { r0 = nx * c0 + ox * s0; r1 = ny * c1 + oy * s1; }
  *(float2*)(ptr + 2 * l) = make_float2(r0, r1);
}

// ---------------- MFMA flash attention (causal, GQA), split-bf16 ----------------
__global__ __launch_bounds__(256) void attn_kernel(const float* __restrict__ qb,
                                                   const float* __restrict__ kbuf,
                                                   const float* __restrict__ vbuf,
                                                   float* __restrict__ ctx) {
  int qt = blockIdx.x, h = blockIdx.y, b = blockIdx.z;
  int kvh = h >> 2;
  int tid = threadIdx.x, l = tid & 63, wid = tid >> 6;
  int lr = l & 15, lk = (l >> 4) * 8;
  __shared__ unsigned short Kh[64 * 136], Kl[64 * 136];   // also used to stage Q
  __shared__ unsigned short Vh[128 * 72], Vl[128 * 72];   // transposed: [dim][key]
  __shared__ unsigned short Ph[64 * 72], Pl[64 * 72];
  int qt0 = qt * 64;

  // stage Q tile (split) into Kh/Kl
  #pragma unroll
  for (int i = 0; i < 8; ++i) {
    int idx = i * 256 + tid;
    int r = idx >> 5, c4 = idx & 31;
    float4 v = *(const float4*)(qb + ((size_t)((b * SS_ + qt0 + r) * H_ + h)) * HD_ + c4 * 4);
    float qv[4] = {v.x, v.y, v.z, v.w};
    #pragma unroll
    for (int e = 0; e < 4; ++e)
      split2(qv[e], Kh[r * 136 + c4 * 4 + e], Kl[r * 136 + c4 * 4 + e]);
  }
  __syncthreads();
  short8 qfh[4], qfl[4];
  #pragma unroll
  for (int t = 0; t < 4; ++t) {
    qfh[t] = *(const short8*)&Kh[(wid * 16 + lr) * 136 + t * 32 + lk];
    qfl[t] = *(const short8*)&Kl[(wid * 16 + lr) * 136 + t * 32 + lk];
  }

  float m[4], sum[4];
  #pragma unroll
  for (int r = 0; r < 4; ++r) { m[r] = -__builtin_inff(); sum[r] = 0.f; }
  floatx4 o[8];
  #pragma unroll
  for (int cb = 0; cb < 8; ++cb) o[cb] = (floatx4){0.f, 0.f, 0.f, 0.f};

  for (int kt = 0; kt <= qt; ++kt) {
    int k0 = kt * 64;
    __syncthreads();  // previous compute done (and q-frag loads on iter 0)
    #pragma unroll
    for (int i = 0; i < 8; ++i) {
      int idx = i * 256 + tid;
      int r = idx >> 5, c4 = idx & 31;
      size_t kvrow = ((size_t)((b * SS_ + k0 + r) * KVH_ + kvh)) * HD_ + c4 * 4;
      float4 kv = *(const float4*)(kbuf + kvrow);
      float kvv[4] = {kv.x, kv.y, kv.z, kv.w};
      #pragma unroll
      for (int e = 0; e < 4; ++e)
        split2(kvv[e], Kh[r * 136 + c4 * 4 + e], Kl[r * 136 + c4 * 4 + e]);
      float4 vv = *(const float4*)(vbuf + kvrow);
      float vvv[4] = {vv.x, vv.y, vv.z, vv.w};
      #pragma unroll
      for (int e = 0; e < 4; ++e)
        split2(vvv[e], Vh[(c4 * 4 + e) * 72 + r], Vl[(c4 * 4 + e) * 72 + r]);
    }
    __syncthreads();

    // scores: 16 queries x 64 keys per wave
    float sv[4][4];
    #pragma unroll
    for (int kbk = 0; kbk < 4; ++kbk) {
      floatx4 s = (floatx4){0.f, 0.f, 0.f, 0.f};
      #pragma unroll
      for (int t = 0; t < 4; ++t) {
        short8 kfh = *(const short8*)&Kh[(kbk * 16 + lr) * 136 + t * 32 + lk];
        short8 kfl = *(const short8*)&Kl[(kbk * 16 + lr) * 136 + t * 32 + lk];
        s = __builtin_amdgcn_mfma_f32_16x16x32_bf16(qfh[t], kfh, s, 0, 0, 0);
        s = __builtin_amdgcn_mfma_f32_16x16x32_bf16(qfh[t], kfl, s, 0, 0, 0);
        s = __builtin_amdgcn_mfma_f32_16x16x32_bf16(qfl[t], kfh, s, 0, 0, 0);
      }
      int key = k0 + kbk * 16 + lr;
      #pragma unroll
      for (int r = 0; r < 4; ++r) {
        int q = qt0 + wid * 16 + (l >> 4) * 4 + r;
        float x = s[r] * 0.08838834764831845f;
        sv[kbk][r] = (key <= q) ? x : -1e30f;
      }
    }
    // online softmax per query row
    float f[4], p[4][4];
    #pragma unroll
    for (int r = 0; r < 4; ++r) {
      float tm = fmaxf(fmaxf(sv[0][r], sv[1][r]), fmaxf(sv[2][r], sv[3][r]));
      tm = fmaxf(tm, __shfl_xor(tm, 1));
      tm = fmaxf(tm, __shfl_xor(tm, 2));
      tm = fmaxf(tm, __shfl_xor(tm, 4));
      tm = fmaxf(tm, __shfl_xor(tm, 8));
      float mn = fmaxf(m[r], tm);
      f[r] = __expf(m[r] - mn);
      m[r] = mn;
      float rs = 0.f;
      #pragma unroll
      for (int kbk = 0; kbk < 4; ++kbk) { p[kbk][r] = __expf(sv[kbk][r] - mn); rs += p[kbk][r]; }
      rs += __shfl_xor(rs, 1); rs += __shfl_xor(rs, 2);
      rs += __shfl_xor(rs, 4); rs += __shfl_xor(rs, 8);
      sum[r] = sum[r] * f[r] + rs;
    }
    // P -> LDS (split)
    #pragma unroll
    for (int kbk = 0; kbk < 4; ++kbk)
      #pragma unroll
      for (int r = 0; r < 4; ++r)
        split2(p[kbk][r],
               Ph[(wid * 16 + (l >> 4) * 4 + r) * 72 + kbk * 16 + lr],
               Pl[(wid * 16 + (l >> 4) * 4 + r) * 72 + kbk * 16 + lr]);
    // rescale accumulators
    #pragma unroll
    for (int cb = 0; cb < 8; ++cb)
      #pragma unroll
      for (int r = 0; r < 4; ++r) o[cb][r] = o[cb][r] * f[r];
    __syncthreads();  // P visible to all (wave-local anyway), keep tidy
    // PV
    short8 pa0h = *(const short8*)&Ph[(wid * 16 + lr) * 72 + lk];
    short8 pa0l = *(const short8*)&Pl[(wid * 16 + lr) * 72 + lk];
    short8 pa1h = *(const short8*)&Ph[(wid * 16 + lr) * 72 + 32 + lk];
    short8 pa1l = *(const short8*)&Pl[(wid * 16 + lr) * 72 + 32 + lk];
    #pragma unroll
    for (int cb = 0; cb < 8; ++cb) {
      short8 vb0h = *(const short8*)&Vh[(cb * 16 + lr) * 72 + lk];
      short8 vb0l = *(const short8*)&Vl[(cb * 16 + lr) * 72 + lk];
      short8 vb1h = *(const short8*)&Vh[(cb * 16 + lr) * 72 + 32 + lk];
      short8 vb1l = *(const short8*)&Vl[(cb * 16 + lr) * 72 + 32 + lk];
      o[cb] = __builtin_amdgcn_mfma_f32_16x16x32_bf16(pa0h, vb0h, o[cb], 0, 0, 0);
      o[cb] = __builtin_amdgcn_mfma_f32_16x16x32_bf16(pa0h, vb0l, o[cb], 0, 0, 0);
      o[cb] = __builtin_amdgcn_mfma_f32_16x16x32_bf16(pa0l, vb0h, o[cb], 0, 0, 0);
      o[cb] = __builtin_amdgcn_mfma_f32_16x16x32_bf16(pa1h, vb1h, o[cb], 0, 0, 0);
      o[cb] = __builtin_amdgcn_mfma_f32_16x16x32_bf16(pa1h, vb1l, o[cb], 0, 0, 0);
      o[cb] = __builtin_amdgcn_mfma_f32_16x16x32_bf16(pa1l, vb1h, o[cb], 0, 0, 0);
    }
  }
  // epilogue: ctx = o / sum (fp32)
  #pragma unroll
  for (int cb = 0; cb < 8; ++cb)
    #pragma unroll
    for (int r = 0; r < 4; ++r) {
      int q = qt0 + wid * 16 + (l >> 4) * 4 + r;
      int d = cb * 16 + lr;
      ctx[((size_t)(b * SS_ + q)) * (H_ * HD_) + h * HD_ + d] = o[cb][r] / sum[r];
    }
}

// ---------------- Router: logits = x2 @ gate_w  (one wave per token, fp32) ----------------
__global__ __launch_bounds__(256) void router_kernel(const float* __restrict__ x2,
                                                     const float* __restrict__ gw,
                                                     float* __restrict__ logits) {
  int t = blockIdx.x * 4 + (threadIdx.x >> 6);
  int l = threadIdx.x & 63;
  float acc[32];
  #pragma unroll
  for (int e = 0; e < 32; ++e) acc[e] = 0.f;
  for (int i = 0; i < 32; ++i) {
    int d = i * 64 + l;
    float xv = x2[(size_t)t * D_ + d];
    const float4* wr = (const float4*)(gw + (size_t)d * E_);
    #pragma unroll
    for (int j = 0; j < 8; ++j) {
      float4 wv = wr[j];
      acc[4 * j + 0] += xv * wv.x; acc[4 * j + 1] += xv * wv.y;
      acc[4 * j + 2] += xv * wv.z; acc[4 * j + 3] += xv * wv.w;
    }
  }
  #pragma unroll
  for (int e = 0; e < 32; ++e) {
    acc[e] += __shfl_xor(acc[e], 1);  acc[e] += __shfl_xor(acc[e], 2);
    acc[e] += __shfl_xor(acc[e], 4);  acc[e] += __shfl_xor(acc[e], 8);
    acc[e] += __shfl_xor(acc[e], 16); acc[e] += __shfl_xor(acc[e], 32);
  }
  if (l == 0) {
    #pragma unroll
    for (int e = 0; e < 32; ++e) logits[(size_t)t * E_ + e] = acc[e];
  }
}

// ---------------- top-8 + softmax + expert counting ----------------
__global__ void topk_kernel(const float* __restrict__ logits, int* __restrict__ sel,
                            float* __restrict__ wts, int* __restrict__ counts) {
  int t = blockIdx.x * blockDim.x + threadIdx.x;
  if (t >= NT_) return;
  float v[32];
  for (int e = 0; e < 32; ++e) v[e] = logits[(size_t)t * E_ + e];
  float val[8]; int idx[8];
  for (int k = 0; k < 8; ++k) {
    float best = -__builtin_inff(); int bi = 0;
    for (int e = 0; e < 32; ++e) if (v[e] > best) { best = v[e]; bi = e; }
    val[k] = best; idx[k] = bi; v[bi] = -__builtin_inff();
  }
  float mx = val[0], s = 0.f; float ex[8];
  for (int k = 0; k < 8; ++k) { ex[k] = expf(val[k] - mx); s += ex[k]; }
  float inv = 1.f / s;
  for (int k = 0; k < 8; ++k) {
    sel[t * 8 + k] = idx[k];
    wts[t * 8 + k] = ex[k] * inv;
    atomicAdd(&counts[idx[k]], 1);
  }
}

__global__ void scan_kernel(const int* __restrict__ counts, int* __restrict__ offs,
                            int* __restrict__ cursors) {
  if (threadIdx.x == 0) {
    int c = 0;
    for (int e = 0; e < E_; ++e) { offs[e] = c; cursors[e] = c; c += counts[e]; }
  }
}

__global__ void scatter_kernel(const int* __restrict__ sel, const float* __restrict__ wts,
                               int* __restrict__ cursors, int* __restrict__ pair_t,
                               float* __restrict__ pair_w) {
  int g = blockIdx.x * blockDim.x + threadIdx.x;
  if (g >= NPAIR_) return;
  int e = sel[g];
  int p = atomicAdd(&cursors[e], 1);
  pair_t[p] = g >> 3;
  pair_w[p] = wts[g];
}

// ---------------- fused gate+up expert GEMM -> act = silu(g)*u (fp32), split-bf16 ----------------
__global__ __launch_bounds__(256) void gateup_kernel(const float* __restrict__ x2,
                                                     const float* __restrict__ gp,
                                                     const float* __restrict__ up,
                                                     const int* __restrict__ counts,
                                                     const int* __restrict__ offs,
                                                     const int* __restrict__ pair_t,
                                                     float* __restrict__ act) {
  int e = blockIdx.z;
  int cnt = counts[e];
  int r0 = blockIdx.y * 64;
  if (r0 >= cnt) return;
  int base = offs[e];
  int n0 = blockIdx.x * 64;
  const float* Bg = gp + (size_t)e * ((size_t)D_ * F_);
  const float* Bu = up + (size_t)e * ((size_t)D_ * F_);
  __shared__ unsigned short Ah[64 * LDA_], Al[64 * LDA_];
  __shared__ unsigned short Gh[64 * LDA_], Gl[64 * LDA_];
  __shared__ unsigned short Uh[64 * LDA_], Ul[64 * LDA_];
  int tid = threadIdx.x, l = tid & 63, wid = tid >> 6;
  int lr = l & 15, lk = (l >> 4) * 8;
  int wr = (wid >> 1) * 32, wc = (wid & 1) * 32;
  int ar = tid >> 2, akq = (tid & 3) * 8;
  int bkr = tid >> 3, bnq = (tid & 7) * 8;
  int arow = r0 + ar; if (arow > cnt - 1) arow = cnt - 1;
  int tokA = pair_t[base + arow];
  const float* Arow = x2 + (size_t)tokA * D_ + akq;
  floatx4 ag[2][2], au[2][2];
  #pragma unroll
  for (int i = 0; i < 2; ++i)
    #pragma unroll
    for (int j = 0; j < 2; ++j) { ag[i][j] = (floatx4){0.f,0.f,0.f,0.f}; au[i][j] = (floatx4){0.f,0.f,0.f,0.f}; }
  for (int k0 = 0; k0 < D_; k0 += 32) {
    float4 a0 = *(const float4*)(Arow + k0);
    float4 a1 = *(const float4*)(Arow + k0 + 4);
    const float* bg = Bg + (size_t)(k0 + bkr) * F_ + n0 + bnq;
    float4 g0 = *(const float4*)bg, g1 = *(const float4*)(bg + 4);
    const float* bu = Bu + (size_t)(k0 + bkr) * F_ + n0 + bnq;
    float4 u0 = *(const float4*)bu, u1 = *(const float4*)(bu + 4);
    __syncthreads();
    float av[8] = {a0.x,a0.y,a0.z,a0.w,a1.x,a1.y,a1.z,a1.w};
    float gv[8] = {g0.x,g0.y,g0.z,g0.w,g1.x,g1.y,g1.z,g1.w};
    float uv[8] = {u0.x,u0.y,u0.z,u0.w,u1.x,u1.y,u1.z,u1.w};
    #pragma unroll
    for (int ee = 0; ee < 8; ++ee) {
      split2(av[ee], Ah[ar * LDA_ + akq + ee], Al[ar * LDA_ + akq + ee]);
      split2(gv[ee], Gh[(bnq + ee) * LDA_ + bkr], Gl[(bnq + ee) * LDA_ + bkr]);
      split2(uv[ee], Uh[(bnq + ee) * LDA_ + bkr], Ul[(bnq + ee) * LDA_ + bkr]);
    }
    __syncthreads();
    short8 af0h = *(const short8*)&Ah[(wr + lr) * LDA_ + lk];
    short8 af0l = *(const short8*)&Al[(wr + lr) * LDA_ + lk];
    short8 af1h = *(const short8*)&Ah[(wr + 16 + lr) * LDA_ + lk];
    short8 af1l = *(const short8*)&Al[(wr + 16 + lr) * LDA_ + lk];
    short8 gf0h = *(const short8*)&Gh[(wc + lr) * LDA_ + lk];
    short8 gf0l = *(const short8*)&Gl[(wc + lr) * LDA_ + lk];
    short8 gf1h = *(const short8*)&Gh[(wc + 16 + lr) * LDA_ + lk];
    short8 gf1l = *(const short8*)&Gl[(wc + 16 + lr) * LDA_ + lk];
    short8 uf0h = *(const short8*)&Uh[(wc + lr) * LDA_ + lk];
    short8 uf0l = *(const short8*)&Ul[(wc + lr) * LDA_ + lk];
    short8 uf1h = *(const short8*)&Uh[(wc + 16 + lr) * LDA_ + lk];
    short8 uf1l = *(const short8*)&Ul[(wc + 16 + lr) * LDA_ + lk];
    ag[0][0] = __builtin_amdgcn_mfma_f32_16x16x32_bf16(af0h, gf0h, ag[0][0], 0, 0, 0);
    ag[0][0] = __builtin_amdgcn_mfma_f32_16x16x32_bf16(af0h, gf0l, ag[0][0], 0, 0, 0);
    ag[0][0] = __builtin_amdgcn_mfma_f32_16x16x32_bf16(af0l, gf0h, ag[0][0], 0, 0, 0);
    ag[0][1] = __builtin_amdgcn_mfma_f32_16x16x32_bf16(af0h, gf1h, ag[0][1], 0, 0, 0);
    ag[0][1] = __builtin_amdgcn_mfma_f32_16x16x32_bf16(af0h, gf1l, ag[0][1], 0, 0, 0);
    ag[0][1] = __builtin_amdgcn_mfma_f32_16x16x32_bf16(af0l, gf1h, ag[0][1], 0, 0, 0);
    ag[1][0] = __builtin_amdgcn_mfma_f32_16x16x32_bf16(af1h, gf0h, ag[1][0], 0, 0, 0);
    ag[1][0] = __builtin_amdgcn_mfma_f32_16x16x32_bf16(af1h, gf0l, ag[1][0], 0, 0, 0);
    ag[1][0] = __builtin_amdgcn_mfma_f32_16x16x32_bf16(af1l, gf0h, ag[1][0], 0, 0, 0);
    ag[1][1] = __builtin_amdgcn_mfma_f32_16x16x32_bf16(af1h, gf1h, ag[1][1], 0, 0, 0);
    ag[1][1] = __builtin_amdgcn_mfma_f32_16x16x32_bf16(af1h, gf1l, ag[1][1], 0, 0, 0);
    ag[1][1] = __builtin_amdgcn_mfma_f32_16x16x32_bf16(af1l, gf1h, ag[1][1], 0, 0, 0);
    au[0][0] = __builtin_amdgcn_mfma_f32_16x16x32_bf16(af0h, uf0h, au[0][0], 0, 0, 0);
    au[0][0] = __builtin_amdgcn_mfma_f32_16x16x32_bf16(af0h, uf0l, au[0][0], 0, 0, 0);
    au[0][0] = __builtin_amdgcn_mfma_f32_16x16x32_bf16(af0l, uf0h, au[0][0], 0, 0, 0);
    au[0][1] = __builtin_amdgcn_mfma_f32_16x16x32_bf16(af0h, uf1h, au[0][1], 0, 0, 0);
    au[0][1] = __builtin_amdgcn_mfma_f32_16x16x32_bf16(af0h, uf1l, au[0][1], 0, 0, 0);
    au[0][1] = __builtin_amdgcn_mfma_f32_16x16x32_bf16(af0l, uf1h, au[0][1], 0, 0, 0);
    au[1][0] = __builtin_amdgcn_mfma_f32_16x16x32_bf16(af1h, uf0h, au[1][0], 0, 0, 0);
    au[1][0] = __builtin_amdgcn_mfma_f32_16x16x32_bf16(af1h, uf0l, au[1][0], 0, 0, 0);
    au[1][0] = __builtin_amdgcn_mfma_f32_16x16x32_bf16(af1l, uf0h, au[1][0], 0, 0, 0);
    au[1][1] = __builtin_amdgcn_mfma_f32_16x16x32_bf16(af1h, uf1h, au[1][1], 0, 0, 0);
    au[1][1] = __builtin_amdgcn_mfma_f32_16x16x32_bf16(af1h, uf1l, au[1][1], 0, 0, 0);
    au[1][1] = __builtin_amdgcn_mfma_f32_16x16x32_bf16(af1l, uf1h, au[1][1], 0, 0, 0);
  }
  int rq = (l >> 4) * 4;
  #pragma unroll
  for (int i = 0; i < 2; ++i)
    #pragma unroll
    for (int r = 0; r < 4; ++r) {
      int rl = wr + i * 16 + rq + r;
      if (r0 + rl < cnt) {
        size_t orow = (size_t)(base + r0 + rl) * F_;
        #pragma unroll
        for (int j = 0; j < 2; ++j) {
          float g = ag[i][j][r], u = au[i][j][r];
          float a = (g / (1.f + __expf(-g))) * u;
          act[orow + n0 + wc + j * 16 + lr] = a;
        }
      }
    }
}

// ---------------- down expert GEMM: scaled atomic accumulate into out, split-bf16 ----------------
__global__ __launch_bounds__(256) void down_kernel(const float* __restrict__ act,
                                                   const float* __restrict__ dw,
                                                   const int* __restrict__ counts,
                                                   const int* __restrict__ offs,
                                                   const int* __restrict__ pair_t,
                                                   const float* __restrict__ pair_w,
                                                   float* __restrict__ out) {
  int e = blockIdx.z;
  int cnt = counts[e];
  int r0 = blockIdx.y * 64;
  if (r0 >= cnt) return;
  int base = offs[e];
  int n0 = blockIdx.x * 64;
  const float* B = dw + (size_t)e * ((size_t)F_ * D_);
  __shared__ unsigned short Ah[64 * LDA_], Al[64 * LDA_];
  __shared__ unsigned short Bh[64 * LDA_], Bl[64 * LDA_];
  int tid = threadIdx.x, l = tid & 63, wid = tid >> 6;
  int lr = l & 15, lk = (l >> 4) * 8;
  int wr = (wid >> 1) * 32, wc = (wid & 1) * 32;
  int ar = tid >> 2, akq = (tid & 3) * 8;
  int bkr = tid >> 3, bnq = (tid & 7) * 8;
  int arow = r0 + ar; if (arow > cnt - 1) arow = cnt - 1;
  const float* Arow = act + (size_t)(base + arow) * F_ + akq;
  floatx4 acc[2][2];
  #pragma unroll
  for (int i = 0; i < 2; ++i)
    #pragma unroll
    for (int j = 0; j < 2; ++j) acc[i][j] = (floatx4){0.f, 0.f, 0.f, 0.f};
  for (int k0 = 0; k0 < F_; k0 += 32) {
    float4 a0 = *(const float4*)(Arow + k0);
    float4 a1 = *(const float4*)(Arow + k0 + 4);
    const float* bp = B + (size_t)(k0 + bkr) * D_ + n0 + bnq;
    float4 b0 = *(const float4*)bp;
    float4 b1 = *(const float4*)(bp + 4);
    __syncthreads();
    float av[8] = {a0.x,a0.y,a0.z,a0.w,a1.x,a1.y,a1.z,a1.w};
    float bv[8] = {b0.x,b0.y,b0.z,b0.w,b1.x,b1.y,b1.z,b1.w};
    #pragma unroll
    for (int ee = 0; ee < 8; ++ee) {
      split2(av[ee], Ah[ar * LDA_ + akq + ee], Al[ar * LDA_ + akq + ee]);
      split2(bv[ee], Bh[(bnq + ee) * LDA_ + bkr], Bl[(bnq + ee) * LDA_ + bkr]);
    }
    __syncthreads();
    short8 af0h = *(const short8*)&Ah[(wr + lr) * LDA_ + lk];
    short8 af0l = *(const short8*)&Al[(wr + lr) * LDA_ + lk];
    short8 af1h = *(const short8*)&Ah[(wr + 16 + lr) * LDA_ + lk];
    short8 af1l = *(const short8*)&Al[(wr + 16 + lr) * LDA_ + lk];
    short8 bf0h = *(const short8*)&Bh[(wc + lr) * LDA_ + lk];
    short8 bf0l = *(const short8*)&Bl[(wc + lr) * LDA_ + lk];
    short8 bf1h = *(const short8*)&Bh[(wc + 16 + lr) * LDA_ + lk];
    short8 bf1l = *(const short8*)&Bl[(wc + 16 + lr) * LDA_ + lk];
    acc[0][0] = __builtin_amdgcn_mfma_f32_16x16x32_bf16(af0h, bf0h, acc[0][0], 0, 0, 0);
    acc[0][0] = __builtin_amdgcn_mfma_f32_16x16x32_bf16(af0h, bf0l, acc[0][0], 0, 0, 0);
    acc[0][0] = __builtin_amdgcn_mfma_f32_16x16x32_bf16(af0l, bf0h, acc[0][0], 0, 0, 0);
    acc[0][1] = __builtin_amdgcn_mfma_f32_16x16x32_bf16(af0h, bf1h, acc[0][1], 0, 0, 0);
    acc[0][1] = __builtin_amdgcn_mfma_f32_16x16x32_bf16(af0h, bf1l, acc[0][1], 0, 0, 0);
    acc[0][1] = __builtin_amdgcn_mfma_f32_16x16x32_bf16(af0l, bf1h, acc[0][1], 0, 0, 0);
    acc[1][0] = __builtin_amdgcn_mfma_f32_16x16x32_bf16(af1h, bf0h, acc[1][0], 0, 0, 0);
    acc[1][0] = __builtin_amdgcn_mfma_f32_16x16x32_bf16(af1h, bf0l, acc[1][0], 0, 0, 0);
    acc[1][0] = __builtin_amdgcn_mfma_f32_16x16x32_bf16(af1l, bf0h, acc[1][0], 0, 0, 0);
    acc[1][1] = __builtin_amdgcn_mfma_f32_16x16x32_bf16(af1h, bf1h, acc[1][1], 0, 0, 0);
    acc[1][1] = __builtin_amdgcn_mfma_f32_16x16x32_bf16(af1h, bf1l, acc[1][1], 0, 0, 0);
    acc[1][1] = __builtin_amdgcn_mfma_f32_16x16x32_bf16(af1l, bf1h, acc[1][1], 0, 0, 0);
  }
  int rq = (l >> 4) * 4;
  #pragma unroll
  for (int i = 0; i < 2; ++i)
    #pragma unroll
    for (int r = 0; r < 4; ++r) {
      int rl = wr + i * 16 + rq + r;
      if (r0 + rl < cnt) {
        int p = base + r0 + rl;
        int tk = pair_t[p];
        float wgt = pair_w[p];
        #pragma unroll
        for (int j = 0; j < 2; ++j)
          atomicAdd(out + (size_t)tk * D_ + n0 + wc + j * 16 + lr, acc[i][j][r] * wgt);
      }
    }
}

// ---------------- launch ----------------
extern "C" void kernel_launch(void* const* d_in, const int* in_sizes, int n_in,
                              void* d_out, int out_size, void* d_ws, size_t ws_size,
                              hipStream_t stream) {
  const float* hidden  = (const float*)d_in[0];
  const float* in_ln   = (const float*)d_in[2];
  const float* post_ln = (const float*)d_in[3];
  const float* q_w     = (const float*)d_in[4];
  const float* k_w     = (const float*)d_in[5];
  const float* v_w     = (const float*)d_in[6];
  const float* o_w     = (const float*)d_in[7];
  const float* q_ns    = (const float*)d_in[8];
  const float* k_ns    = (const float*)d_in[9];
  const float* gate_w  = (const float*)d_in[10];
  const float* gate_p  = (const float*)d_in[11];
  const float* up_p    = (const float*)d_in[12];
  const float* down_p  = (const float*)d_in[13];
  float* out = (float*)d_out;

  char* w = (char*)d_ws;
  size_t off = 0;
  auto alloc = [&](size_t b) { char* p = w + off; off += (b + 255) & ~(size_t)255; return p; };
  float* h_ln  = (float*)alloc((size_t)NT_ * D_ * 4);
  float* qbuf  = (float*)alloc((size_t)NT_ * H_ * HD_ * 4);
  float* kbuf  = (float*)alloc((size_t)NT_ * KVH_ * HD_ * 4);
  float* vbuf  = (float*)alloc((size_t)NT_ * KVH_ * HD_ * 4);
  float* ctx   = (float*)alloc((size_t)NT_ * H_ * HD_ * 4);
  float* x2    = (float*)alloc((size_t)NT_ * D_ * 4);
  float* logits = (float*)alloc((size_t)NT_ * E_ * 4);
  int*   sel    = (int*)alloc((size_t)NT_ * TOPK_ * 4);
  float* wts    = (float*)alloc((size_t)NT_ * TOPK_ * 4);
  int*   counts = (int*)alloc(E_ * 4);
  int*   offs   = (int*)alloc(E_ * 4);
  int*   curs   = (int*)alloc(E_ * 4);
  int*   pair_t = (int*)alloc((size_t)NPAIR_ * 4);
  float* pair_w = (float*)alloc((size_t)NPAIR_ * 4);
  float* act    = (float*)alloc((size_t)NPAIR_ * F_ * 4);

  rms_kernel<<<NT_, 256, 0, stream>>>(hidden, in_ln, h_ln);
  gemm_kernel<0><<<dim3(32, 32), 256, 0, stream>>>(h_ln, q_w, nullptr, qbuf, NT_, 2048, 2048);
  gemm_kernel<0><<<dim3(8, 32), 256, 0, stream>>>(h_ln, k_w, nullptr, kbuf, NT_, 512, 2048);
  gemm_kernel<0><<<dim3(8, 32), 256, 0, stream>>>(h_ln, v_w, nullptr, vbuf, NT_, 512, 2048);
  qknorm_rope_kernel<<<(NT_ * (H_ + KVH_)) / 4, 256, 0, stream>>>(qbuf, kbuf, q_ns, k_ns);
  attn_kernel<<<dim3(SS_ / 64, H_, NB_), 256, 0, stream>>>(qbuf, kbuf, vbuf, ctx);
  gemm_kernel<1><<<dim3(32, 32), 256, 0, stream>>>(ctx, o_w, hidden, out, NT_, 2048, 2048);
  rms_kernel<<<NT_, 256, 0, stream>>>(out, post_ln, x2);
  (void)hipMemsetAsync(counts, 0, E_ * 4, stream);
  router_kernel<<<NT_ / 4, 256, 0, stream>>>(x2, gate_w, logits);
  topk_kernel<<<NT_ / 256, 256, 0, stream>>>(logits, sel, wts, counts);
  scan_kernel<<<1, 64, 0, stream>>>(counts, offs, curs);
  scatter_kernel<<<NPAIR_ / 256, 256, 0, stream>>>(sel, wts, curs, pair_t, pair_w);
  gateup_kernel<<<dim3(F_ / 64, 32, E_), 256, 0, stream>>>(x2, gate_p, up_p, counts, offs, pair_t, act);
  down_kernel<<<dim3(D_ / 64, 32, E_), 256, 0, stream>>>(act, down_p, counts, offs, pair_t, pair_w, out);
}

// Round 3
// 1193.091 us; speedup vs baseline: 1.9932x; 1.9932x over previous
//
#include <hip/hip_runtime.h>
#include <hip/hip_bf16.h>

#define D_ 2048
#define H_ 16
#define KVH_ 4
#define HD_ 128
#define E_ 32
#define TOPK_ 8
#define F_ 768
#define NB_ 2
#define SS_ 1024
#define NT_ 2048
#define NPAIR_ 16384

typedef __attribute__((ext_vector_type(8))) short short8;
typedef __attribute__((ext_vector_type(4))) float floatx4;
typedef __attribute__((ext_vector_type(4))) unsigned int uintx4;
typedef __attribute__((ext_vector_type(4))) unsigned short ushortx4;

__device__ __forceinline__ unsigned short f2bf(float f) {
  union { float f; unsigned u; } v; v.f = f;
  unsigned r = v.u + 0x7FFFu + ((v.u >> 16) & 1u);
  return (unsigned short)(r >> 16);
}
__device__ __forceinline__ float bf2f(unsigned short h) {
  union { unsigned u; float f; } v; v.u = ((unsigned)h) << 16;
  return v.f;
}
__device__ __forceinline__ void split2(float v, unsigned short& hi, unsigned short& lo) {
  unsigned short h = f2bf(v);
  hi = h;
  lo = f2bf(v - bf2f(h));
}

// ---------------- weight transpose + convert: fp32 [R][C] -> bf16 [C][R] ----------------
__global__ __launch_bounds__(256) void tconv_kernel(const float* __restrict__ src,
                                                    unsigned short* __restrict__ dst,
                                                    int R, int C) {
  size_t off = (size_t)blockIdx.z * R * C;
  src += off; dst += off;
  __shared__ float t[32][33];
  int c0 = blockIdx.x * 32, r0 = blockIdx.y * 32;
  int row = threadIdx.x >> 3, c4 = (threadIdx.x & 7) * 4;
  float4 v = *(const float4*)(src + (size_t)(r0 + row) * C + c0 + c4);
  t[row][c4 + 0] = v.x; t[row][c4 + 1] = v.y; t[row][c4 + 2] = v.z; t[row][c4 + 3] = v.w;
  __syncthreads();
  ushortx4 o = { f2bf(t[c4 + 0][row]), f2bf(t[c4 + 1][row]),
                 f2bf(t[c4 + 2][row]), f2bf(t[c4 + 3][row]) };
  *(ushortx4*)(dst + (size_t)(c0 + row) * R + r0 + c4) = o;
}

// ---------------- weight transpose + split: fp32 [R][C] -> hi/lo bf16 [C][R] ----------------
__global__ __launch_bounds__(256) void tsplit_kernel(const float* __restrict__ src,
                                                     unsigned short* __restrict__ dhi,
                                                     unsigned short* __restrict__ dlo,
                                                     int R, int C) {
  __shared__ float t[32][33];
  int c0 = blockIdx.x * 32, r0 = blockIdx.y * 32;
  int row = threadIdx.x >> 3, c4 = (threadIdx.x & 7) * 4;
  float4 v = *(const float4*)(src + (size_t)(r0 + row) * C + c0 + c4);
  t[row][c4 + 0] = v.x; t[row][c4 + 1] = v.y; t[row][c4 + 2] = v.z; t[row][c4 + 3] = v.w;
  __syncthreads();
  ushortx4 oh, ol;
  #pragma unroll
  for (int i = 0; i < 4; ++i) {
    unsigned short hi, lo;
    split2(t[c4 + i][row], hi, lo);
    oh[i] = hi; ol[i] = lo;
  }
  size_t didx = (size_t)(c0 + row) * R + r0 + c4;
  *(ushortx4*)(dhi + didx) = oh;
  *(ushortx4*)(dlo + didx) = ol;
}

// ---------------- RMSNorm. MODE 0: -> hi/lo bf16. MODE 1: -> fp32 + hi bf16 ----------------
template<int MODE>
__global__ __launch_bounds__(256) void rms_kernel(const float* __restrict__ in,
                                                  const float* __restrict__ sc,
                                                  float* __restrict__ outf,
                                                  unsigned short* __restrict__ o1,
                                                  unsigned short* __restrict__ o2) {
  __shared__ float red[4];
  int row = blockIdx.x, tid = threadIdx.x;
  const float4* x4 = (const float4*)(in + (size_t)row * D_);
  float4 a = x4[tid], b = x4[tid + 256];
  float ss = a.x*a.x + a.y*a.y + a.z*a.z + a.w*a.w
           + b.x*b.x + b.y*b.y + b.z*b.z + b.w*b.w;
  #pragma unroll
  for (int off = 1; off < 64; off <<= 1) ss += __shfl_xor(ss, off);
  if ((tid & 63) == 0) red[tid >> 6] = ss;
  __syncthreads();
  float r = rsqrtf((red[0] + red[1] + red[2] + red[3]) * (1.0f / D_) + 1e-6f);
  const float4* s4 = (const float4*)sc;
  float4 sa = s4[tid], sb = s4[tid + 256];
  float va[8] = { a.x*r*sa.x, a.y*r*sa.y, a.z*r*sa.z, a.w*r*sa.w,
                  b.x*r*sb.x, b.y*r*sb.y, b.z*r*sb.z, b.w*r*sb.w };
  if (MODE == 0) {
    ushortx4 h0, l0, h1, l1;
    #pragma unroll
    for (int i = 0; i < 4; ++i) { unsigned short h, l; split2(va[i], h, l); h0[i] = h; l0[i] = l; }
    #pragma unroll
    for (int i = 0; i < 4; ++i) { unsigned short h, l; split2(va[4 + i], h, l); h1[i] = h; l1[i] = l; }
    *(ushortx4*)(o1 + (size_t)row * D_ + tid * 4) = h0;
    *(ushortx4*)(o2 + (size_t)row * D_ + tid * 4) = l0;
    *(ushortx4*)(o1 + (size_t)row * D_ + 1024 + tid * 4) = h1;
    *(ushortx4*)(o2 + (size_t)row * D_ + 1024 + tid * 4) = l1;
  } else {
    *(float4*)(outf + (size_t)row * D_ + tid * 4) = make_float4(va[0], va[1], va[2], va[3]);
    *(float4*)(outf + (size_t)row * D_ + 1024 + tid * 4) = make_float4(va[4], va[5], va[6], va[7]);
    ushortx4 h0 = { f2bf(va[0]), f2bf(va[1]), f2bf(va[2]), f2bf(va[3]) };
    ushortx4 h1 = { f2bf(va[4]), f2bf(va[5]), f2bf(va[6]), f2bf(va[7]) };
    *(ushortx4*)(o1 + (size_t)row * D_ + tid * 4) = h0;
    *(ushortx4*)(o1 + (size_t)row * D_ + 1024 + tid * 4) = h1;
  }
}

// ---------------- split GEMM: A hi/lo [M][K], B hi/lo [N][K] -> fp32 (3-term) ----------------
template<int EPI>
__global__ __launch_bounds__(256) void gemm_bb(const unsigned short* __restrict__ Ahi,
                                               const unsigned short* __restrict__ Alo,
                                               const unsigned short* __restrict__ Bhi,
                                               const unsigned short* __restrict__ Blo,
                                               const float* __restrict__ res,
                                               float* __restrict__ out,
                                               int M, int Nn, int K) {
  __shared__ unsigned short Ah[64 * 72], Al[64 * 72], Bh[64 * 72], Bl[64 * 72];
  int tid = threadIdx.x, l = tid & 63, wid = tid >> 6;
  int lr = l & 15, lk = (l >> 4) * 8;
  int m0 = blockIdx.y * 64, n0 = blockIdx.x * 64;
  int wr = (wid >> 1) * 32, wc = (wid & 1) * 32;
  int srow = tid >> 3, sch = (tid & 7) * 8;
  size_t aoff[2], boff[2];
  int loff[2];
  #pragma unroll
  for (int i = 0; i < 2; ++i) {
    aoff[i] = (size_t)(m0 + i * 32 + srow) * K + sch;
    boff[i] = (size_t)(n0 + i * 32 + srow) * K + sch;
    loff[i] = (i * 32 + srow) * 72 + sch;
  }
  floatx4 acc[2][2];
  #pragma unroll
  for (int i = 0; i < 2; ++i)
    #pragma unroll
    for (int j = 0; j < 2; ++j) acc[i][j] = (floatx4){0.f, 0.f, 0.f, 0.f};
  for (int k0 = 0; k0 < K; k0 += 64) {
    uintx4 vah[2], val[2], vbh[2], vbl[2];
    #pragma unroll
    for (int i = 0; i < 2; ++i) {
      vah[i] = *(const uintx4*)(Ahi + aoff[i] + k0);
      val[i] = *(const uintx4*)(Alo + aoff[i] + k0);
      vbh[i] = *(const uintx4*)(Bhi + boff[i] + k0);
      vbl[i] = *(const uintx4*)(Blo + boff[i] + k0);
    }
    __syncthreads();
    #pragma unroll
    for (int i = 0; i < 2; ++i) {
      *(uintx4*)&Ah[loff[i]] = vah[i];
      *(uintx4*)&Al[loff[i]] = val[i];
      *(uintx4*)&Bh[loff[i]] = vbh[i];
      *(uintx4*)&Bl[loff[i]] = vbl[i];
    }
    __syncthreads();
    #pragma unroll
    for (int ks = 0; ks < 2; ++ks) {
      short8 ah[2], al_[2], bh[2], bl_[2];
      #pragma unroll
      for (int i = 0; i < 2; ++i) {
        ah[i]  = *(const short8*)&Ah[(wr + i * 16 + lr) * 72 + ks * 32 + lk];
        al_[i] = *(const short8*)&Al[(wr + i * 16 + lr) * 72 + ks * 32 + lk];
        bh[i]  = *(const short8*)&Bh[(wc + i * 16 + lr) * 72 + ks * 32 + lk];
        bl_[i] = *(const short8*)&Bl[(wc + i * 16 + lr) * 72 + ks * 32 + lk];
      }
      #pragma unroll
      for (int i = 0; i < 2; ++i)
        #pragma unroll
        for (int j = 0; j < 2; ++j) {
          acc[i][j] = __builtin_amdgcn_mfma_f32_16x16x32_bf16(ah[i], bh[j], acc[i][j], 0, 0, 0);
          acc[i][j] = __builtin_amdgcn_mfma_f32_16x16x32_bf16(ah[i], bl_[j], acc[i][j], 0, 0, 0);
          acc[i][j] = __builtin_amdgcn_mfma_f32_16x16x32_bf16(al_[i], bh[j], acc[i][j], 0, 0, 0);
        }
    }
  }
  int rq = (l >> 4) * 4;
  #pragma unroll
  for (int i = 0; i < 2; ++i)
    #pragma unroll
    for (int j = 0; j < 2; ++j)
      #pragma unroll
      for (int r = 0; r < 4; ++r) {
        size_t idx = (size_t)(m0 + wr + i * 16 + rq + r) * Nn + (n0 + wc + j * 16 + lr);
        float v = acc[i][j][r];
        if (EPI == 1) v += res[idx];
        out[idx] = v;
      }
}

// ---------------- per-head RMSNorm + RoPE (in-place, fp32) ----------------
__global__ __launch_bounds__(256) void qknorm_rope_kernel(float* __restrict__ qb,
                                                          float* __restrict__ kb,
                                                          const float* __restrict__ qs,
                                                          const float* __restrict__ ks) {
  int gw = blockIdx.x * 4 + (threadIdx.x >> 6);
  int l = threadIdx.x & 63;
  float* ptr; const float* sc; int t;
  if (gw < NT_ * H_) { ptr = qb + (size_t)gw * HD_; sc = qs; t = gw >> 4; }
  else { int r = gw - NT_ * H_; ptr = kb + (size_t)r * HD_; sc = ks; t = r >> 2; }
  int pos = t & (SS_ - 1);
  float2 x = *(float2*)(ptr + 2 * l);
  float p2 = x.x * x.x + x.y * x.y;
  #pragma unroll
  for (int off = 1; off < 64; off <<= 1) p2 += __shfl_xor(p2, off);
  float rms = rsqrtf(p2 * (1.0f / HD_) + 1e-6f);
  float nx = x.x * rms * sc[2 * l];
  float ny = x.y * rms * sc[2 * l + 1];
  int j0 = (2 * l) & 63;
  float ang0 = pos * __expf(-(float)j0 * (13.815510557964274f / 64.0f));
  float ang1 = pos * __expf(-(float)(j0 + 1) * (13.815510557964274f / 64.0f));
  float s0, c0, s1, c1;
  sincosf(ang0, &s0, &c0);
  sincosf(ang1, &s1, &c1);
  float ox = __shfl_xor(nx, 32);
  float oy = __shfl_xor(ny, 32);
  float r0, r1;
  if (l < 32) { r0 = nx * c0 - ox * s0; r1 = ny * c1 - oy * s1; }
  else        { r0 = nx * c0 + ox * s0; r1 = ny * c1 + oy * s1; }
  *(float2*)(ptr + 2 * l) = make_float2(r0, r1);
}

// ---------------- MFMA flash attention (causal, GQA), split-bf16 ----------------
__global__ __launch_bounds__(256) void attn_kernel(const float* __restrict__ qb,
                                                   const float* __restrict__ kbuf,
                                                   const float* __restrict__ vbuf,
                                                   unsigned short* __restrict__ ctx_hi,
                                                   unsigned short* __restrict__ ctx_lo) {
  int qt = blockIdx.x, h = blockIdx.y, b = blockIdx.z;
  int kvh = h >> 2;
  int tid = threadIdx.x, l = tid & 63, wid = tid >> 6;
  int lr = l & 15, lk = (l >> 4) * 8;
  __shared__ unsigned short Kh[64 * 136], Kl[64 * 136];
  __shared__ unsigned short Vh[128 * 72], Vl[128 * 72];
  __shared__ unsigned short Ph[64 * 72], Pl[64 * 72];
  int qt0 = qt * 64;

  #pragma unroll
  for (int i = 0; i < 8; ++i) {
    int idx = i * 256 + tid;
    int r = idx >> 5, c4 = idx & 31;
    float4 v = *(const float4*)(qb + ((size_t)((b * SS_ + qt0 + r) * H_ + h)) * HD_ + c4 * 4);
    float qv[4] = {v.x, v.y, v.z, v.w};
    #pragma unroll
    for (int e = 0; e < 4; ++e)
      split2(qv[e], Kh[r * 136 + c4 * 4 + e], Kl[r * 136 + c4 * 4 + e]);
  }
  __syncthreads();
  short8 qfh[4], qfl[4];
  #pragma unroll
  for (int t = 0; t < 4; ++t) {
    qfh[t] = *(const short8*)&Kh[(wid * 16 + lr) * 136 + t * 32 + lk];
    qfl[t] = *(const short8*)&Kl[(wid * 16 + lr) * 136 + t * 32 + lk];
  }

  float m[4], sum[4];
  #pragma unroll
  for (int r = 0; r < 4; ++r) { m[r] = -__builtin_inff(); sum[r] = 0.f; }
  floatx4 o[8];
  #pragma unroll
  for (int cb = 0; cb < 8; ++cb) o[cb] = (floatx4){0.f, 0.f, 0.f, 0.f};

  for (int kt = 0; kt <= qt; ++kt) {
    int k0 = kt * 64;
    __syncthreads();
    #pragma unroll
    for (int i = 0; i < 8; ++i) {
      int idx = i * 256 + tid;
      int r = idx >> 5, c4 = idx & 31;
      size_t kvrow = ((size_t)((b * SS_ + k0 + r) * KVH_ + kvh)) * HD_ + c4 * 4;
      float4 kv = *(const float4*)(kbuf + kvrow);
      float kvv[4] = {kv.x, kv.y, kv.z, kv.w};
      #pragma unroll
      for (int e = 0; e < 4; ++e)
        split2(kvv[e], Kh[r * 136 + c4 * 4 + e], Kl[r * 136 + c4 * 4 + e]);
      float4 vv = *(const float4*)(vbuf + kvrow);
      float vvv[4] = {vv.x, vv.y, vv.z, vv.w};
      #pragma unroll
      for (int e = 0; e < 4; ++e)
        split2(vvv[e], Vh[(c4 * 4 + e) * 72 + r], Vl[(c4 * 4 + e) * 72 + r]);
    }
    __syncthreads();

    float sv[4][4];
    #pragma unroll
    for (int kbk = 0; kbk < 4; ++kbk) {
      floatx4 s = (floatx4){0.f, 0.f, 0.f, 0.f};
      #pragma unroll
      for (int t = 0; t < 4; ++t) {
        short8 kfh = *(const short8*)&Kh[(kbk * 16 + lr) * 136 + t * 32 + lk];
        short8 kfl = *(const short8*)&Kl[(kbk * 16 + lr) * 136 + t * 32 + lk];
        s = __builtin_amdgcn_mfma_f32_16x16x32_bf16(qfh[t], kfh, s, 0, 0, 0);
        s = __builtin_amdgcn_mfma_f32_16x16x32_bf16(qfh[t], kfl, s, 0, 0, 0);
        s = __builtin_amdgcn_mfma_f32_16x16x32_bf16(qfl[t], kfh, s, 0, 0, 0);
      }
      int key = k0 + kbk * 16 + lr;
      #pragma unroll
      for (int r = 0; r < 4; ++r) {
        int q = qt0 + wid * 16 + (l >> 4) * 4 + r;
        float x = s[r] * 0.08838834764831845f;
        sv[kbk][r] = (key <= q) ? x : -1e30f;
      }
    }
    float f[4], p[4][4];
    #pragma unroll
    for (int r = 0; r < 4; ++r) {
      float tm = fmaxf(fmaxf(sv[0][r], sv[1][r]), fmaxf(sv[2][r], sv[3][r]));
      tm = fmaxf(tm, __shfl_xor(tm, 1));
      tm = fmaxf(tm, __shfl_xor(tm, 2));
      tm = fmaxf(tm, __shfl_xor(tm, 4));
      tm = fmaxf(tm, __shfl_xor(tm, 8));
      float mn = fmaxf(m[r], tm);
      f[r] = __expf(m[r] - mn);
      m[r] = mn;
      float rs = 0.f;
      #pragma unroll
      for (int kbk = 0; kbk < 4; ++kbk) { p[kbk][r] = __expf(sv[kbk][r] - mn); rs += p[kbk][r]; }
      rs += __shfl_xor(rs, 1); rs += __shfl_xor(rs, 2);
      rs += __shfl_xor(rs, 4); rs += __shfl_xor(rs, 8);
      sum[r] = sum[r] * f[r] + rs;
    }
    #pragma unroll
    for (int kbk = 0; kbk < 4; ++kbk)
      #pragma unroll
      for (int r = 0; r < 4; ++r)
        split2(p[kbk][r],
               Ph[(wid * 16 + (l >> 4) * 4 + r) * 72 + kbk * 16 + lr],
               Pl[(wid * 16 + (l >> 4) * 4 + r) * 72 + kbk * 16 + lr]);
    #pragma unroll
    for (int cb = 0; cb < 8; ++cb)
      #pragma unroll
      for (int r = 0; r < 4; ++r) o[cb][r] = o[cb][r] * f[r];
    __syncthreads();
    short8 pa0h = *(const short8*)&Ph[(wid * 16 + lr) * 72 + lk];
    short8 pa0l = *(const short8*)&Pl[(wid * 16 + lr) * 72 + lk];
    short8 pa1h = *(const short8*)&Ph[(wid * 16 + lr) * 72 + 32 + lk];
    short8 pa1l = *(const short8*)&Pl[(wid * 16 + lr) * 72 + 32 + lk];
    #pragma unroll
    for (int cb = 0; cb < 8; ++cb) {
      short8 vb0h = *(const short8*)&Vh[(cb * 16 + lr) * 72 + lk];
      short8 vb0l = *(const short8*)&Vl[(cb * 16 + lr) * 72 + lk];
      short8 vb1h = *(const short8*)&Vh[(cb * 16 + lr) * 72 + 32 + lk];
      short8 vb1l = *(const short8*)&Vl[(cb * 16 + lr) * 72 + 32 + lk];
      o[cb] = __builtin_amdgcn_mfma_f32_16x16x32_bf16(pa0h, vb0h, o[cb], 0, 0, 0);
      o[cb] = __builtin_amdgcn_mfma_f32_16x16x32_bf16(pa0h, vb0l, o[cb], 0, 0, 0);
      o[cb] = __builtin_amdgcn_mfma_f32_16x16x32_bf16(pa0l, vb0h, o[cb], 0, 0, 0);
      o[cb] = __builtin_amdgcn_mfma_f32_16x16x32_bf16(pa1h, vb1h, o[cb], 0, 0, 0);
      o[cb] = __builtin_amdgcn_mfma_f32_16x16x32_bf16(pa1h, vb1l, o[cb], 0, 0, 0);
      o[cb] = __builtin_amdgcn_mfma_f32_16x16x32_bf16(pa1l, vb1h, o[cb], 0, 0, 0);
    }
  }
  #pragma unroll
  for (int cb = 0; cb < 8; ++cb)
    #pragma unroll
    for (int r = 0; r < 4; ++r) {
      int q = qt0 + wid * 16 + (l >> 4) * 4 + r;
      int d = cb * 16 + lr;
      float val = o[cb][r] / sum[r];
      unsigned short hi, lo;
      split2(val, hi, lo);
      size_t idx = ((size_t)(b * SS_ + q)) * (H_ * HD_) + h * HD_ + d;
      ctx_hi[idx] = hi;
      ctx_lo[idx] = lo;
    }
}

// ---------------- Router (fp32) ----------------
__global__ __launch_bounds__(256) void router_kernel(const float* __restrict__ x2,
                                                     const float* __restrict__ gw,
                                                     float* __restrict__ logits) {
  int t = blockIdx.x * 4 + (threadIdx.x >> 6);
  int l = threadIdx.x & 63;
  float acc[32];
  #pragma unroll
  for (int e = 0; e < 32; ++e) acc[e] = 0.f;
  for (int i = 0; i < 32; ++i) {
    int d = i * 64 + l;
    float xv = x2[(size_t)t * D_ + d];
    const float4* wr = (const float4*)(gw + (size_t)d * E_);
    #pragma unroll
    for (int j = 0; j < 8; ++j) {
      float4 wv = wr[j];
      acc[4 * j + 0] += xv * wv.x; acc[4 * j + 1] += xv * wv.y;
      acc[4 * j + 2] += xv * wv.z; acc[4 * j + 3] += xv * wv.w;
    }
  }
  #pragma unroll
  for (int e = 0; e < 32; ++e) {
    acc[e] += __shfl_xor(acc[e], 1);  acc[e] += __shfl_xor(acc[e], 2);
    acc[e] += __shfl_xor(acc[e], 4);  acc[e] += __shfl_xor(acc[e], 8);
    acc[e] += __shfl_xor(acc[e], 16); acc[e] += __shfl_xor(acc[e], 32);
  }
  if (l == 0) {
    #pragma unroll
    for (int e = 0; e < 32; ++e) logits[(size_t)t * E_ + e] = acc[e];
  }
}

// ---------------- top-8 + softmax + expert counting ----------------
__global__ void topk_kernel(const float* __restrict__ logits, int* __restrict__ sel,
                            float* __restrict__ wts, int* __restrict__ counts) {
  int t = blockIdx.x * blockDim.x + threadIdx.x;
  if (t >= NT_) return;
  float v[32];
  for (int e = 0; e < 32; ++e) v[e] = logits[(size_t)t * E_ + e];
  float val[8]; int idx[8];
  for (int k = 0; k < 8; ++k) {
    float best = -__builtin_inff(); int bi = 0;
    for (int e = 0; e < 32; ++e) if (v[e] > best) { best = v[e]; bi = e; }
    val[k] = best; idx[k] = bi; v[bi] = -__builtin_inff();
  }
  float mx = val[0], s = 0.f; float ex[8];
  for (int k = 0; k < 8; ++k) { ex[k] = expf(val[k] - mx); s += ex[k]; }
  float inv = 1.f / s;
  for (int k = 0; k < 8; ++k) {
    sel[t * 8 + k] = idx[k];
    wts[t * 8 + k] = ex[k] * inv;
    atomicAdd(&counts[idx[k]], 1);
  }
}

__global__ void scan_kernel(const int* __restrict__ counts, int* __restrict__ offs,
                            int* __restrict__ cursors) {
  if (threadIdx.x == 0) {
    int c = 0;
    for (int e = 0; e < E_; ++e) { offs[e] = c; cursors[e] = c; c += counts[e]; }
  }
}

__global__ void scatter_kernel(const int* __restrict__ sel, const float* __restrict__ wts,
                               int* __restrict__ cursors, int* __restrict__ pair_t,
                               float* __restrict__ pair_w) {
  int g = blockIdx.x * blockDim.x + threadIdx.x;
  if (g >= NPAIR_) return;
  int e = sel[g];
  int p = atomicAdd(&cursors[e], 1);
  pair_t[p] = g >> 3;
  pair_w[p] = wts[g];
}

// ---------------- gate+up expert GEMM (bf16), act = silu(g)*u*pw -> bf16 ----------------
__global__ __launch_bounds__(256) void gateup_kernel(const unsigned short* __restrict__ xbf,
                                                     const unsigned short* __restrict__ gT,
                                                     const unsigned short* __restrict__ uT,
                                                     const int* __restrict__ counts,
                                                     const int* __restrict__ offs,
                                                     const int* __restrict__ pair_t,
                                                     const float* __restrict__ pair_w,
                                                     unsigned short* __restrict__ act) {
  int e = blockIdx.z;
  int cnt = counts[e];
  int r0 = blockIdx.y * 128;
  if (r0 >= cnt) return;
  int base = offs[e];
  int n0 = blockIdx.x * 64;
  const unsigned short* G = gT + (size_t)e * F_ * D_;
  const unsigned short* U = uT + (size_t)e * F_ * D_;
  __shared__ unsigned short As[128 * 72], Gs[64 * 72], Us[64 * 72];
  int tid = threadIdx.x, l = tid & 63, wid = tid >> 6;
  int lr = l & 15, lk = (l >> 4) * 8;
  int wr = (wid >> 1) * 64, wc = (wid & 1) * 32;
  int srow = tid >> 3, sch = (tid & 7) * 8;
  const unsigned short* arp[4];
  int alds[4];
  #pragma unroll
  for (int i = 0; i < 4; ++i) {
    int rr = i * 32 + srow;
    int cr = r0 + rr; if (cr > cnt - 1) cr = cnt - 1;
    arp[i] = xbf + (size_t)pair_t[base + cr] * D_ + sch;
    alds[i] = rr * 72 + sch;
  }
  size_t goff[2];
  int glds[2];
  #pragma unroll
  for (int i = 0; i < 2; ++i) {
    int rr = i * 32 + srow;
    goff[i] = (size_t)(n0 + rr) * D_ + sch;
    glds[i] = rr * 72 + sch;
  }
  floatx4 ag[4][2], au[4][2];
  #pragma unroll
  for (int i = 0; i < 4; ++i)
    #pragma unroll
    for (int j = 0; j < 2; ++j) { ag[i][j] = (floatx4){0.f,0.f,0.f,0.f}; au[i][j] = (floatx4){0.f,0.f,0.f,0.f}; }
  for (int k0 = 0; k0 < D_; k0 += 64) {
    uintx4 va[4], vg[2], vu[2];
    #pragma unroll
    for (int i = 0; i < 4; ++i) va[i] = *(const uintx4*)(arp[i] + k0);
    #pragma unroll
    for (int i = 0; i < 2; ++i) {
      vg[i] = *(const uintx4*)(G + goff[i] + k0);
      vu[i] = *(const uintx4*)(U + goff[i] + k0);
    }
    __syncthreads();
    #pragma unroll
    for (int i = 0; i < 4; ++i) *(uintx4*)&As[alds[i]] = va[i];
    #pragma unroll
    for (int i = 0; i < 2; ++i) {
      *(uintx4*)&Gs[glds[i]] = vg[i];
      *(uintx4*)&Us[glds[i]] = vu[i];
    }
    __syncthreads();
    #pragma unroll
    for (int ks = 0; ks < 2; ++ks) {
      short8 a[4], g[2], u[2];
      #pragma unroll
      for (int i = 0; i < 4; ++i)
        a[i] = *(const short8*)&As[(wr + i * 16 + lr) * 72 + ks * 32 + lk];
      #pragma unroll
      for (int j = 0; j < 2; ++j) {
        g[j] = *(const short8*)&Gs[(wc + j * 16 + lr) * 72 + ks * 32 + lk];
        u[j] = *(const short8*)&Us[(wc + j * 16 + lr) * 72 + ks * 32 + lk];
      }
      #pragma unroll
      for (int i = 0; i < 4; ++i)
        #pragma unroll
        for (int j = 0; j < 2; ++j) {
          ag[i][j] = __builtin_amdgcn_mfma_f32_16x16x32_bf16(a[i], g[j], ag[i][j], 0, 0, 0);
          au[i][j] = __builtin_amdgcn_mfma_f32_16x16x32_bf16(a[i], u[j], au[i][j], 0, 0, 0);
        }
    }
  }
  int rq = (l >> 4) * 4;
  #pragma unroll
  for (int i = 0; i < 4; ++i)
    #pragma unroll
    for (int r = 0; r < 4; ++r) {
      int rowl = wr + i * 16 + rq + r;
      if (r0 + rowl < cnt) {
        int p = base + r0 + rowl;
        float pw = pair_w[p];
        size_t orow = (size_t)p * F_;
        #pragma unroll
        for (int j = 0; j < 2; ++j) {
          float g = ag[i][j][r], u = au[i][j][r];
          float a = (g / (1.f + __expf(-g))) * u * pw;
          act[orow + n0 + wc + j * 16 + lr] = f2bf(a);
        }
      }
    }
}

// ---------------- down expert GEMM (bf16): atomic accumulate into out ----------------
__global__ __launch_bounds__(256) void down_kernel(const unsigned short* __restrict__ act,
                                                   const unsigned short* __restrict__ dT,
                                                   const int* __restrict__ counts,
                                                   const int* __restrict__ offs,
                                                   const int* __restrict__ pair_t,
                                                   float* __restrict__ out) {
  int e = blockIdx.z;
  int cnt = counts[e];
  int r0 = blockIdx.y * 128;
  if (r0 >= cnt) return;
  int base = offs[e];
  int n0 = blockIdx.x * 64;
  const unsigned short* B = dT + (size_t)e * ((size_t)D_ * F_);
  __shared__ unsigned short As[128 * 72], Bs[64 * 72];
  int tid = threadIdx.x, l = tid & 63, wid = tid >> 6;
  int lr = l & 15, lk = (l >> 4) * 8;
  int wr = (wid >> 1) * 64, wc = (wid & 1) * 32;
  int srow = tid >> 3, sch = (tid & 7) * 8;
  size_t aoff[4]; int alds[4];
  #pragma unroll
  for (int i = 0; i < 4; ++i) {
    int rr = i * 32 + srow;
    int cr = r0 + rr; if (cr > cnt - 1) cr = cnt - 1;
    aoff[i] = (size_t)(base + cr) * F_ + sch;
    alds[i] = rr * 72 + sch;
  }
  size_t boff[2]; int blds[2];
  #pragma unroll
  for (int i = 0; i < 2; ++i) {
    int rr = i * 32 + srow;
    boff[i] = (size_t)(n0 + rr) * F_ + sch;
    blds[i] = rr * 72 + sch;
  }
  floatx4 acc[4][2];
  #pragma unroll
  for (int i = 0; i < 4; ++i)
    #pragma unroll
    for (int j = 0; j < 2; ++j) acc[i][j] = (floatx4){0.f, 0.f, 0.f, 0.f};
  for (int k0 = 0; k0 < F_; k0 += 64) {
    uintx4 va[4], vb[2];
    #pragma unroll
    for (int i = 0; i < 4; ++i) va[i] = *(const uintx4*)(act + aoff[i] + k0);
    #pragma unroll
    for (int i = 0; i < 2; ++i) vb[i] = *(const uintx4*)(B + boff[i] + k0);
    __syncthreads();
    #pragma unroll
    for (int i = 0; i < 4; ++i) *(uintx4*)&As[alds[i]] = va[i];
    #pragma unroll
    for (int i = 0; i < 2; ++i) *(uintx4*)&Bs[blds[i]] = vb[i];
    __syncthreads();
    #pragma unroll
    for (int ks = 0; ks < 2; ++ks) {
      short8 a[4], b[2];
      #pragma unroll
      for (int i = 0; i < 4; ++i)
        a[i] = *(const short8*)&As[(wr + i * 16 + lr) * 72 + ks * 32 + lk];
      #pragma unroll
      for (int j = 0; j < 2; ++j)
        b[j] = *(const short8*)&Bs[(wc + j * 16 + lr) * 72 + ks * 32 + lk];
      #pragma unroll
      for (int i = 0; i < 4; ++i)
        #pragma unroll
        for (int j = 0; j < 2; ++j)
          acc[i][j] = __builtin_amdgcn_mfma_f32_16x16x32_bf16(a[i], b[j], acc[i][j], 0, 0, 0);
    }
  }
  int rq = (l >> 4) * 4;
  #pragma unroll
  for (int i = 0; i < 4; ++i)
    #pragma unroll
    for (int r = 0; r < 4; ++r) {
      int rowl = wr + i * 16 + rq + r;
      if (r0 + rowl < cnt) {
        int p = base + r0 + rowl;
        int tk = pair_t[p];
        #pragma unroll
        for (int j = 0; j < 2; ++j)
          atomicAdd(out + (size_t)tk * D_ + n0 + wc + j * 16 + lr, acc[i][j][r]);
      }
    }
}

// ---------------- launch ----------------
extern "C" void kernel_launch(void* const* d_in, const int* in_sizes, int n_in,
                              void* d_out, int out_size, void* d_ws, size_t ws_size,
                              hipStream_t stream) {
  const float* hidden  = (const float*)d_in[0];
  const float* in_ln   = (const float*)d_in[2];
  const float* post_ln = (const float*)d_in[3];
  const float* q_w     = (const float*)d_in[4];
  const float* k_w     = (const float*)d_in[5];
  const float* v_w     = (const float*)d_in[6];
  const float* o_w     = (const float*)d_in[7];
  const float* q_ns    = (const float*)d_in[8];
  const float* k_ns    = (const float*)d_in[9];
  const float* gate_w  = (const float*)d_in[10];
  const float* gate_p  = (const float*)d_in[11];
  const float* up_p    = (const float*)d_in[12];
  const float* down_p  = (const float*)d_in[13];
  float* out = (float*)d_out;

  char* w = (char*)d_ws;
  size_t off = 0;
  auto alloc = [&](size_t b) { char* p = w + off; off += (b + 255) & ~(size_t)255; return p; };
  unsigned short* qThi = (unsigned short*)alloc((size_t)2048 * 2048 * 2);
  unsigned short* qTlo = (unsigned short*)alloc((size_t)2048 * 2048 * 2);
  unsigned short* kThi = (unsigned short*)alloc((size_t)512 * 2048 * 2);
  unsigned short* kTlo = (unsigned short*)alloc((size_t)512 * 2048 * 2);
  unsigned short* vThi = (unsigned short*)alloc((size_t)512 * 2048 * 2);
  unsigned short* vTlo = (unsigned short*)alloc((size_t)512 * 2048 * 2);
  unsigned short* oThi = (unsigned short*)alloc((size_t)2048 * 2048 * 2);
  unsigned short* oTlo = (unsigned short*)alloc((size_t)2048 * 2048 * 2);
  unsigned short* gT   = (unsigned short*)alloc((size_t)E_ * F_ * D_ * 2);
  unsigned short* uT   = (unsigned short*)alloc((size_t)E_ * F_ * D_ * 2);
  unsigned short* dT   = (unsigned short*)alloc((size_t)E_ * D_ * F_ * 2);
  unsigned short* h_hi = (unsigned short*)alloc((size_t)NT_ * D_ * 2);
  unsigned short* h_lo = (unsigned short*)alloc((size_t)NT_ * D_ * 2);
  float* qbuf  = (float*)alloc((size_t)NT_ * H_ * HD_ * 4);
  float* kbuf  = (float*)alloc((size_t)NT_ * KVH_ * HD_ * 4);
  float* vbuf  = (float*)alloc((size_t)NT_ * KVH_ * HD_ * 4);
  unsigned short* ctx_hi = (unsigned short*)alloc((size_t)NT_ * H_ * HD_ * 2);
  unsigned short* ctx_lo = (unsigned short*)alloc((size_t)NT_ * H_ * HD_ * 2);
  float* x2    = (float*)alloc((size_t)NT_ * D_ * 4);
  unsigned short* x2bf = (unsigned short*)alloc((size_t)NT_ * D_ * 2);
  float* logits = (float*)alloc((size_t)NT_ * E_ * 4);
  int*   sel    = (int*)alloc((size_t)NT_ * TOPK_ * 4);
  float* wts    = (float*)alloc((size_t)NT_ * TOPK_ * 4);
  int*   counts = (int*)alloc(E_ * 4);
  int*   offs   = (int*)alloc(E_ * 4);
  int*   curs   = (int*)alloc(E_ * 4);
  int*   pair_t = (int*)alloc((size_t)NPAIR_ * 4);
  float* pair_w = (float*)alloc((size_t)NPAIR_ * 4);
  unsigned short* act = (unsigned short*)alloc((size_t)NPAIR_ * F_ * 2);

  // weight prep
  tsplit_kernel<<<dim3(64, 64), 256, 0, stream>>>(q_w, qThi, qTlo, 2048, 2048);
  tsplit_kernel<<<dim3(16, 64), 256, 0, stream>>>(k_w, kThi, kTlo, 2048, 512);
  tsplit_kernel<<<dim3(16, 64), 256, 0, stream>>>(v_w, vThi, vTlo, 2048, 512);
  tsplit_kernel<<<dim3(64, 64), 256, 0, stream>>>(o_w, oThi, oTlo, 2048, 2048);
  tconv_kernel<<<dim3(24, 64, 32), 256, 0, stream>>>(gate_p, gT, 2048, 768);
  tconv_kernel<<<dim3(24, 64, 32), 256, 0, stream>>>(up_p, uT, 2048, 768);
  tconv_kernel<<<dim3(64, 24, 32), 256, 0, stream>>>(down_p, dT, 768, 2048);

  rms_kernel<0><<<NT_, 256, 0, stream>>>(hidden, in_ln, nullptr, h_hi, h_lo);
  gemm_bb<0><<<dim3(32, 32), 256, 0, stream>>>(h_hi, h_lo, qThi, qTlo, nullptr, qbuf, NT_, 2048, 2048);
  gemm_bb<0><<<dim3(8, 32), 256, 0, stream>>>(h_hi, h_lo, kThi, kTlo, nullptr, kbuf, NT_, 512, 2048);
  gemm_bb<0><<<dim3(8, 32), 256, 0, stream>>>(h_hi, h_lo, vThi, vTlo, nullptr, vbuf, NT_, 512, 2048);
  qknorm_rope_kernel<<<(NT_ * (H_ + KVH_)) / 4, 256, 0, stream>>>(qbuf, kbuf, q_ns, k_ns);
  attn_kernel<<<dim3(SS_ / 64, H_, NB_), 256, 0, stream>>>(qbuf, kbuf, vbuf, ctx_hi, ctx_lo);
  gemm_bb<1><<<dim3(32, 32), 256, 0, stream>>>(ctx_hi, ctx_lo, oThi, oTlo, hidden, out, NT_, 2048, 2048);
  rms_kernel<1><<<NT_, 256, 0, stream>>>(out, post_ln, x2, x2bf, nullptr);
  (void)hipMemsetAsync(counts, 0, E_ * 4, stream);
  router_kernel<<<NT_ / 4, 256, 0, stream>>>(x2, gate_w, logits);
  topk_kernel<<<NT_ / 256, 256, 0, stream>>>(logits, sel, wts, counts);
  scan_kernel<<<1, 64, 0, stream>>>(counts, offs, curs);
  scatter_kernel<<<NPAIR_ / 256, 256, 0, stream>>>(sel, wts, curs, pair_t, pair_w);
  gateup_kernel<<<dim3(F_ / 64, 16, E_), 256, 0, stream>>>(x2bf, gT, uT, counts, offs, pair_t, pair_w, act);
  down_kernel<<<dim3(D_ / 64, 16, E_), 256, 0, stream>>>(act, dT, counts, offs, pair_t, out);
}